// Round 6
// baseline (614.426 us; speedup 1.0000x reference)
//
#include <hip/hip_runtime.h>

#define HSZ 32
#define TT  1024
#define LOG2E 1.44269504088896340736f

typedef float v2f __attribute__((ext_vector_type(2)));
typedef float v4f __attribute__((ext_vector_type(4)));

__device__ __forceinline__ float frcp(float x)  { return __builtin_amdgcn_rcpf(x); }
__device__ __forceinline__ float fexp2(float x) { return __builtin_amdgcn_exp2f(x); }

#define LO(v) __builtin_shufflevector((v), (v), 0, 1)
#define HI(v) __builtin_shufflevector((v), (v), 2, 3)

// -------- prep: prescale weights into d_ws, lane-major ----------------------
// Lane l = half*32 + j owns gate rows r1 = (half?2:0)*32+j, r2 = (half?3:1)*32+j.
// ws float layout:
//   [l*64 + 0..31]  = s1 * W_hh[r1][:]      (s1 = -2log2e for g-row, else -log2e)
//   [l*64 + 32..63] = s2 * W_hh[r2][:]      (s2 = -log2e)
//   [4096 + l*4 + {0,1,2,3}] = { s1*(b_ih[r1]+b_hh[r1]), s2*(b_ih[r2]+b_hh[r2]),
//                                s1*W_ih[r1], s2*W_ih[r2] }
__global__ void lstm_prep_kernel(const float* __restrict__ W_ih,
                                 const float* __restrict__ W_hh,
                                 const float* __restrict__ b_ih,
                                 const float* __restrict__ b_hh,
                                 float* __restrict__ ws)
{
  const int lane = threadIdx.x;        // 0..63
  const int half = lane >> 5;
  const int j    = lane & 31;
  const int r1 = (half ? 2 : 0) * HSZ + j;
  const int r2 = (half ? 3 : 1) * HSZ + j;
  const float s1 = half ? (-2.0f * LOG2E) : (-LOG2E);
  const float s2 = -LOG2E;
  for (int k = 0; k < HSZ; ++k) {
    ws[lane * 64 + k]      = s1 * W_hh[r1 * HSZ + k];
    ws[lane * 64 + 32 + k] = s2 * W_hh[r2 * HSZ + k];
  }
  ws[4096 + lane * 4 + 0] = s1 * (b_ih[r1] + b_hh[r1]);
  ws[4096 + lane * 4 + 1] = s2 * (b_ih[r2] + b_hh[r2]);
  ws[4096 + lane * 4 + 2] = s1 * W_ih[r1];
  ws[4096 + lane * 4 + 3] = s2 * W_ih[r2];
}

// -------- main: one wave per batch element ----------------------------------
// Weights are BORN inside a volatile asm block (17x global_load_dwordx4 +
// s_waitcnt) -> LLVM cannot rematerialize them; keep-live or spill-to-scratch
// are its only options. Rounds 1-5 proved every source-level pin gets remat'd
// into per-step L1 reloads (VGPR_Count 60 < the 64-VGPR weight footprint).
__global__ __launch_bounds__(64, 4)
void lstm_fused_kernel(const float* __restrict__ ws,
                       const float* __restrict__ x,
                       const float* __restrict__ W1, const float* __restrict__ b1,
                       const float* __restrict__ W2, const float* __restrict__ b2,
                       const float* __restrict__ W3, const float* __restrict__ b3,
                       float* __restrict__ out)
{
  __shared__ __align__(16) float hlds[2][HSZ];   // row 0 real, row 1 trash

  const int lane = threadIdx.x;          // 0..63 (one wave per block)
  const int half = lane >> 5;            // 0: gates i,f ; 1: gates g,o
  const int j    = lane & 31;
  const int elem = blockIdx.x;

  const float A1 = half ? 2.0f : 1.0f;   // act1 = A1*rcp(1+exp2(z1)) + B1
  const float B1 = half ? -1.0f : 0.0f;  // -> sigm (lower) | tanh (upper)

  // ---- opaque weight materialization: 64 weight VGPRs + 4 consts ----
  const float* wbase = ws + (size_t)lane * 64;
  const float* cbase = ws + 4096 + (size_t)lane * 4;
  v4f wv[16]; v4f cvec;
  asm volatile(
    "global_load_dwordx4 %0,  %17, off\n\t"
    "global_load_dwordx4 %1,  %17, off offset:16\n\t"
    "global_load_dwordx4 %2,  %17, off offset:32\n\t"
    "global_load_dwordx4 %3,  %17, off offset:48\n\t"
    "global_load_dwordx4 %4,  %17, off offset:64\n\t"
    "global_load_dwordx4 %5,  %17, off offset:80\n\t"
    "global_load_dwordx4 %6,  %17, off offset:96\n\t"
    "global_load_dwordx4 %7,  %17, off offset:112\n\t"
    "global_load_dwordx4 %8,  %17, off offset:128\n\t"
    "global_load_dwordx4 %9,  %17, off offset:144\n\t"
    "global_load_dwordx4 %10, %17, off offset:160\n\t"
    "global_load_dwordx4 %11, %17, off offset:176\n\t"
    "global_load_dwordx4 %12, %17, off offset:192\n\t"
    "global_load_dwordx4 %13, %17, off offset:208\n\t"
    "global_load_dwordx4 %14, %17, off offset:224\n\t"
    "global_load_dwordx4 %15, %17, off offset:240\n\t"
    "global_load_dwordx4 %16, %18, off\n\t"
    "s_waitcnt vmcnt(0)"
    : "=&v"(wv[0]),  "=&v"(wv[1]),  "=&v"(wv[2]),  "=&v"(wv[3]),
      "=&v"(wv[4]),  "=&v"(wv[5]),  "=&v"(wv[6]),  "=&v"(wv[7]),
      "=&v"(wv[8]),  "=&v"(wv[9]),  "=&v"(wv[10]), "=&v"(wv[11]),
      "=&v"(wv[12]), "=&v"(wv[13]), "=&v"(wv[14]), "=&v"(wv[15]),
      "=&v"(cvec)
    : "v"(wbase), "v"(cbase)
    : "memory");

  const float bz1  = cvec.x;
  const float bz2  = cvec.y;
  const float wxz1 = cvec.z;
  const float wxz2 = cvec.w;

  float c = 0.0f;
  hlds[half][j] = 0.0f;                  // h0 = 0 (both rows)

  const float* xrow = x + (size_t)elem * TT;

#pragma unroll 1
  for (int t0 = 0; t0 < TT; t0 += 64) {
    float xc = xrow[t0 + lane];          // coalesced: 64 timesteps per load

#pragma unroll 1
    for (int s = 0; s < 64; ++s) {
      float xt = __shfl(xc, s);          // wave-uniform broadcast of x_t

      v2f a1e = (v2f){fmaf(xt, wxz1, bz1), 0.0f};
      v2f a2e = (v2f){fmaf(xt, wxz2, bz2), 0.0f};
      v2f a1o = (v2f){0.0f, 0.0f};
      v2f a2o = (v2f){0.0f, 0.0f};

      const v4f* hv = reinterpret_cast<const v4f*>(&hlds[0][0]);
#pragma unroll
      for (int g = 0; g < 4; ++g) {      // h chunk [8g, 8g+8)
        v4f p = hv[2 * g];
        v4f q = hv[2 * g + 1];
        a1e = __builtin_elementwise_fma(LO(wv[2*g]),     LO(p), a1e);
        a1o = __builtin_elementwise_fma(HI(wv[2*g]),     HI(p), a1o);
        a2e = __builtin_elementwise_fma(LO(wv[8+2*g]),   LO(p), a2e);
        a2o = __builtin_elementwise_fma(HI(wv[8+2*g]),   HI(p), a2o);
        a1e = __builtin_elementwise_fma(LO(wv[2*g+1]),   LO(q), a1e);
        a1o = __builtin_elementwise_fma(HI(wv[2*g+1]),   HI(q), a1o);
        a2e = __builtin_elementwise_fma(LO(wv[8+2*g+1]), LO(q), a2e);
        a2o = __builtin_elementwise_fma(HI(wv[8+2*g+1]), HI(q), a2o);
      }
      v2f a1 = a1e + a1o;
      v2f a2 = a2e + a2o;
      float z1 = a1.x + a1.y;
      float z2 = a2.x + a2.y;

      float act1 = fmaf(A1, frcp(1.0f + fexp2(z1)), B1); // sigm(i) | tanh(g)
      float act2 = frcp(1.0f + fexp2(z2));               // sigm(f) | sigm(o)

      float tg = __shfl_xor(act1, 32);   // lower receives tanh(g)
      float so = __shfl_xor(act2, 32);   // lower receives sigm(o)

      c = fmaf(act2, c, act1 * tg);      // lower: sigm(f)*c + sigm(i)*tanh(g)
      float tc = fmaf(2.0f, frcp(1.0f + fexp2(c * (-2.0f * LOG2E))), -1.0f);
      float h = so * tc;                 // lower: sigm(o)*tanh(c)

      hlds[half][j] = h;                 // upper half -> trash row 1
    }
  }

  // ---- MLP head 32->16->8->1 on final h (LDS row 0), redundant per lane ----
  const float* hrow = &hlds[0][0];
  float a1v[16];
#pragma unroll
  for (int r = 0; r < 16; ++r) {
    float acc = b1[r];
#pragma unroll
    for (int k = 0; k < 32; ++k) acc = fmaf(W1[r * 32 + k], hrow[k], acc);
    a1v[r] = fmaxf(acc, 0.0f);
  }
  float a2v[8];
#pragma unroll
  for (int r = 0; r < 8; ++r) {
    float acc = b2[r];
#pragma unroll
    for (int k = 0; k < 16; ++k) acc = fmaf(W2[r * 16 + k], a1v[k], acc);
    a2v[r] = fmaxf(acc, 0.0f);
  }
  float o = b3[0];
#pragma unroll
  for (int k = 0; k < 8; ++k) o = fmaf(W3[k], a2v[k], o);

  if (lane == 0) out[elem] = o;
}

extern "C" void kernel_launch(void* const* d_in, const int* in_sizes, int n_in,
                              void* d_out, int out_size, void* d_ws, size_t ws_size,
                              hipStream_t stream) {
  const float* x    = (const float*)d_in[0];
  const float* W_ih = (const float*)d_in[1];
  const float* W_hh = (const float*)d_in[2];
  const float* b_ih = (const float*)d_in[3];
  const float* b_hh = (const float*)d_in[4];
  const float* W1   = (const float*)d_in[5];
  const float* b1   = (const float*)d_in[6];
  const float* W2   = (const float*)d_in[7];
  const float* b2   = (const float*)d_in[8];
  const float* W3   = (const float*)d_in[9];
  const float* b3   = (const float*)d_in[10];
  float* out = (float*)d_out;
  float* ws  = (float*)d_ws;                 // needs 4096+256 floats = 17 KB

  const int B = in_sizes[0] / TT;            // 4096

  hipLaunchKernelGGL(lstm_prep_kernel, dim3(1), dim3(64), 0, stream,
                     W_ih, W_hh, b_ih, b_hh, ws);
  hipLaunchKernelGGL(lstm_fused_kernel, dim3(B), dim3(64), 0, stream,
                     ws, x, W1, b1, W2, b2, W3, b3, out);
}

// Round 7
// 499.477 us; speedup vs baseline: 1.2301x; 1.2301x over previous
//
#include <hip/hip_runtime.h>

#define HSZ 32
#define TT  1024
#define LOG2E 1.44269504088896340736f

typedef _Float16     h2  __attribute__((ext_vector_type(2)));
typedef float        v4f __attribute__((ext_vector_type(4)));
typedef unsigned int v4u __attribute__((ext_vector_type(4)));

__device__ __forceinline__ float frcp(float x)  { return __builtin_amdgcn_rcpf(x); }
__device__ __forceinline__ float fexp2(float x) { return __builtin_amdgcn_exp2f(x); }
__device__ __forceinline__ h2    bch2(unsigned int u) { return __builtin_bit_cast(h2, u); }
__device__ __forceinline__ float fdot2(h2 a, h2 b, float c) {
  return __builtin_amdgcn_fdot2(a, b, c, false);
}

// -------- prep: prescale rows, round to f16, pack lane-major ----------------
// Lane l = half*32+j owns rows r1 = (half?2:0)*32+j (i|g), r2 = (half?3:1)*32+j
// (f|o). Row r1 scaled by s1 (-2log2e for g, -log2e else), r2 by s2 = -log2e,
// THEN rounded to f16 pairs. Per-lane ws block: 36 dwords (144 B, 16B-aligned):
//   [0..15]  = r1 as 16 half2 k-pairs
//   [16..31] = r2 as 16 half2 k-pairs
//   [32..35] = f32 { s1*(b_ih[r1]+b_hh[r1]), s2*(b_ih[r2]+b_hh[r2]),
//                    s1*W_ih[r1], s2*W_ih[r2] }
__global__ void lstm_prep_kernel(const float* __restrict__ W_ih,
                                 const float* __restrict__ W_hh,
                                 const float* __restrict__ b_ih,
                                 const float* __restrict__ b_hh,
                                 unsigned int* __restrict__ ws)
{
  const int lane = threadIdx.x;        // 0..63
  const int half = lane >> 5;
  const int j    = lane & 31;
  const int r1 = (half ? 2 : 0) * HSZ + j;
  const int r2 = (half ? 3 : 1) * HSZ + j;
  const float s1 = half ? (-2.0f * LOG2E) : (-LOG2E);
  const float s2 = -LOG2E;
  unsigned int* base = ws + lane * 36;
  union { h2 h; unsigned int u; } cv;
  for (int d = 0; d < 16; ++d) {
    cv.h = (h2){ (_Float16)(s1 * W_hh[r1 * HSZ + 2*d]),
                 (_Float16)(s1 * W_hh[r1 * HSZ + 2*d + 1]) };
    base[d] = cv.u;
    cv.h = (h2){ (_Float16)(s2 * W_hh[r2 * HSZ + 2*d]),
                 (_Float16)(s2 * W_hh[r2 * HSZ + 2*d + 1]) };
    base[16 + d] = cv.u;
  }
  union { float f; unsigned int u; } fu;
  fu.f = s1 * (b_ih[r1] + b_hh[r1]); base[32] = fu.u;
  fu.f = s2 * (b_ih[r2] + b_hh[r2]); base[33] = fu.u;
  fu.f = s1 * W_ih[r1];              base[34] = fu.u;
  fu.f = s2 * W_ih[r2];              base[35] = fu.u;
}

// -------- main: one wave per batch element, v_dot2_f32_f16 recurrence -------
// Lanes 0-31 own gate rows (i,f) of hidden j; lanes 32-63 own (g,o).
// 32 v_dot2 per step replace 64 scalar FMAs; weights are 32 VGPRs of half2
// (small enough that residency is no longer contested). h crosses steps as
// f16 in LDS (4 ds_read_b128 per step). c, x-term, accumulation all fp32.
__global__ __launch_bounds__(64, 4)
void lstm_fused_kernel(const unsigned int* __restrict__ ws,
                       const float* __restrict__ x,
                       const float* __restrict__ W1, const float* __restrict__ b1,
                       const float* __restrict__ W2, const float* __restrict__ b2,
                       const float* __restrict__ W3, const float* __restrict__ b3,
                       float* __restrict__ out)
{
  __shared__ __align__(16) _Float16 hlds[2][HSZ];   // row 0 real, row 1 trash

  const int lane = threadIdx.x;          // 0..63 (one wave per block)
  const int half = lane >> 5;            // 0: gates i,f ; 1: gates g,o
  const int j    = lane & 31;
  const int elem = blockIdx.x;

  const float A1 = half ? 2.0f : 1.0f;   // act1 = A1*rcp(1+exp2(z1)) + B1
  const float B1 = half ? -1.0f : 0.0f;  // -> sigm (lower) | tanh (upper)

  // ---- opaque weight materialization: 8x dwordx4 (32 half2) + consts ----
  const unsigned int* wbase = ws + (size_t)lane * 36;
  v4u wq[8]; v4f cvec;
  asm volatile(
    "global_load_dwordx4 %0, %9, off\n\t"
    "global_load_dwordx4 %1, %9, off offset:16\n\t"
    "global_load_dwordx4 %2, %9, off offset:32\n\t"
    "global_load_dwordx4 %3, %9, off offset:48\n\t"
    "global_load_dwordx4 %4, %9, off offset:64\n\t"
    "global_load_dwordx4 %5, %9, off offset:80\n\t"
    "global_load_dwordx4 %6, %9, off offset:96\n\t"
    "global_load_dwordx4 %7, %9, off offset:112\n\t"
    "global_load_dwordx4 %8, %9, off offset:128\n\t"
    "s_waitcnt vmcnt(0)"
    : "=&v"(wq[0]), "=&v"(wq[1]), "=&v"(wq[2]), "=&v"(wq[3]),
      "=&v"(wq[4]), "=&v"(wq[5]), "=&v"(wq[6]), "=&v"(wq[7]),
      "=&v"(cvec)
    : "v"(wbase)
    : "memory");

  // unpack: wq[0..3] = row r1 pairs (k=0..31), wq[4..7] = row r2 pairs
  h2 w1h[16], w2h[16];
#pragma unroll
  for (int q = 0; q < 4; ++q) {
    w1h[4*q+0] = bch2(wq[q].x);   w1h[4*q+1] = bch2(wq[q].y);
    w1h[4*q+2] = bch2(wq[q].z);   w1h[4*q+3] = bch2(wq[q].w);
    w2h[4*q+0] = bch2(wq[4+q].x); w2h[4*q+1] = bch2(wq[4+q].y);
    w2h[4*q+2] = bch2(wq[4+q].z); w2h[4*q+3] = bch2(wq[4+q].w);
  }
  const float bz1  = cvec.x;
  const float bz2  = cvec.y;
  const float wxz1 = cvec.z;
  const float wxz2 = cvec.w;

  float c = 0.0f;
  hlds[half][j] = (_Float16)0.0f;        // h0 = 0 (both rows)

  const float* xrow = x + (size_t)elem * TT;

#pragma unroll 1
  for (int t0 = 0; t0 < TT; t0 += 64) {
    float xc = xrow[t0 + lane];          // coalesced: 64 timesteps per load

#pragma unroll 1
    for (int s = 0; s < 64; ++s) {
      float xt = __shfl(xc, s);          // wave-uniform broadcast of x_t

      // seed accumulators with bias + x-term (no zero-init movs)
      float a1 = fmaf(xt, wxz1, bz1);
      float a2 = fmaf(xt, wxz2, bz2);

      const v4u* hv = reinterpret_cast<const v4u*>(&hlds[0][0]);  // 32 f16
#pragma unroll
      for (int g = 0; g < 4; ++g) {      // h k-chunk [8g, 8g+8) as 4 half2
        v4u hq = hv[g];
        h2 p0 = bch2(hq.x), p1 = bch2(hq.y), p2 = bch2(hq.z), p3 = bch2(hq.w);
        a1 = fdot2(w1h[4*g+0], p0, a1);
        a2 = fdot2(w2h[4*g+0], p0, a2);
        a1 = fdot2(w1h[4*g+1], p1, a1);
        a2 = fdot2(w2h[4*g+1], p1, a2);
        a1 = fdot2(w1h[4*g+2], p2, a1);
        a2 = fdot2(w2h[4*g+2], p2, a2);
        a1 = fdot2(w1h[4*g+3], p3, a1);
        a2 = fdot2(w2h[4*g+3], p3, a2);
      }

      float act1 = fmaf(A1, frcp(1.0f + fexp2(a1)), B1); // sigm(i) | tanh(g)
      float act2 = frcp(1.0f + fexp2(a2));               // sigm(f) | sigm(o)

      float tg = __shfl_xor(act1, 32);   // lower receives tanh(g)
      float so = __shfl_xor(act2, 32);   // lower receives sigm(o)

      c = fmaf(act2, c, act1 * tg);      // lower: sigm(f)*c + sigm(i)*tanh(g)
      float tc = fmaf(2.0f, frcp(1.0f + fexp2(c * (-2.0f * LOG2E))), -1.0f);
      float h = so * tc;                 // lower: sigm(o)*tanh(c)

      hlds[half][j] = (_Float16)h;       // upper half -> trash row 1
    }
  }

  // ---- MLP head 32->16->8->1 on final h (LDS row 0), redundant per lane ----
  float hf[HSZ];
#pragma unroll
  for (int k = 0; k < HSZ; ++k) hf[k] = (float)hlds[0][k];

  float a1v[16];
#pragma unroll
  for (int r = 0; r < 16; ++r) {
    float acc = b1[r];
#pragma unroll
    for (int k = 0; k < 32; ++k) acc = fmaf(W1[r * 32 + k], hf[k], acc);
    a1v[r] = fmaxf(acc, 0.0f);
  }
  float a2v[8];
#pragma unroll
  for (int r = 0; r < 8; ++r) {
    float acc = b2[r];
#pragma unroll
    for (int k = 0; k < 16; ++k) acc = fmaf(W2[r * 16 + k], a1v[k], acc);
    a2v[r] = fmaxf(acc, 0.0f);
  }
  float o = b3[0];
#pragma unroll
  for (int k = 0; k < 8; ++k) o = fmaf(W3[k], a2v[k], o);

  if (lane == 0) out[elem] = o;
}

extern "C" void kernel_launch(void* const* d_in, const int* in_sizes, int n_in,
                              void* d_out, int out_size, void* d_ws, size_t ws_size,
                              hipStream_t stream) {
  const float* x    = (const float*)d_in[0];
  const float* W_ih = (const float*)d_in[1];
  const float* W_hh = (const float*)d_in[2];
  const float* b_ih = (const float*)d_in[3];
  const float* b_hh = (const float*)d_in[4];
  const float* W1   = (const float*)d_in[5];
  const float* b1   = (const float*)d_in[6];
  const float* W2   = (const float*)d_in[7];
  const float* b2   = (const float*)d_in[8];
  const float* W3   = (const float*)d_in[9];
  const float* b3   = (const float*)d_in[10];
  float* out = (float*)d_out;
  unsigned int* ws = (unsigned int*)d_ws;    // needs 64*36 dwords = 9216 B

  const int B = in_sizes[0] / TT;            // 4096

  hipLaunchKernelGGL(lstm_prep_kernel, dim3(1), dim3(64), 0, stream,
                     W_ih, W_hh, b_ih, b_hh, ws);
  hipLaunchKernelGGL(lstm_fused_kernel, dim3(B), dim3(64), 0, stream,
                     ws, x, W1, b1, W2, b2, W3, b3, out);
}

// Round 10
// 493.955 us; speedup vs baseline: 1.2439x; 1.0112x over previous
//
#include <hip/hip_runtime.h>

#define HSZ 32
#define TT  1024
#define LOG2E 1.44269504088896340736f

typedef _Float16     h2  __attribute__((ext_vector_type(2)));
typedef unsigned int v4u __attribute__((ext_vector_type(4)));

__device__ __forceinline__ float frcp(float x)  { return __builtin_amdgcn_rcpf(x); }
__device__ __forceinline__ float fexp2(float x) { return __builtin_amdgcn_exp2f(x); }
__device__ __forceinline__ h2    bch2(unsigned int u) { return __builtin_bit_cast(h2, u); }
__device__ __forceinline__ float fdot2(h2 a, h2 b, float c) {
  return __builtin_amdgcn_fdot2(a, b, c, false);
}

// -------- prep: prescale rows, round to f16, pack lane-major (R7, proven) ---
// Lane l = half*32+j owns rows r1 = (half?2:0)*32+j (i|g), r2 = (half?3:1)*32+j
// (f|o). Row r1 scaled by s1 (-2log2e for g, -log2e else), r2 by s2 = -log2e,
// THEN rounded to f16 pairs. Per-lane ws block: 36 dwords (144 B):
//   [0..15] = r1 as 16 half2 k-pairs   [16..31] = r2 as 16 half2 k-pairs
//   [32..35] = f32 { s1*(b_ih[r1]+b_hh[r1]), s2*(b_ih[r2]+b_hh[r2]),
//                    s1*W_ih[r1], s2*W_ih[r2] }
__global__ void lstm_prep_kernel(const float* __restrict__ W_ih,
                                 const float* __restrict__ W_hh,
                                 const float* __restrict__ b_ih,
                                 const float* __restrict__ b_hh,
                                 unsigned int* __restrict__ ws)
{
  const int lane = threadIdx.x;        // 0..63
  const int half = lane >> 5;
  const int j    = lane & 31;
  const int r1 = (half ? 2 : 0) * HSZ + j;
  const int r2 = (half ? 3 : 1) * HSZ + j;
  const float s1 = half ? (-2.0f * LOG2E) : (-LOG2E);
  const float s2 = -LOG2E;
  unsigned int* base = ws + lane * 36;
  union { h2 h; unsigned int u; } cv;
  for (int d = 0; d < 16; ++d) {
    cv.h = (h2){ (_Float16)(s1 * W_hh[r1 * HSZ + 2*d]),
                 (_Float16)(s1 * W_hh[r1 * HSZ + 2*d + 1]) };
    base[d] = cv.u;
    cv.h = (h2){ (_Float16)(s2 * W_hh[r2 * HSZ + 2*d]),
                 (_Float16)(s2 * W_hh[r2 * HSZ + 2*d + 1]) };
    base[16 + d] = cv.u;
  }
  union { float f; unsigned int u; } fu;
  fu.f = s1 * (b_ih[r1] + b_hh[r1]); base[32] = fu.u;
  fu.f = s2 * (b_ih[r2] + b_hh[r2]); base[33] = fu.u;
  fu.f = s1 * W_ih[r1];              base[34] = fu.u;
  fu.f = s2 * W_ih[r2];              base[35] = fu.u;
}

// -------- main: one wave per batch element (R7 skeleton, proven) ------------
// Lanes 0-31 own gate rows (i,f) of hidden j; lanes 32-63 own (g,o).
// Deltas vs R7 (both bit-exact): (1) x broadcast via v_readlane (SGPR lane
// select) instead of __shfl's ds_bpermute+wait; (2) step loop unrolled 16x so
// the compiler pipelines weight reloads / LDS reads across steps. Cross-half
// exchange stays __shfl_xor(.,32) — R7-proven semantics.
__global__ __launch_bounds__(64, 4)
void lstm_fused_kernel(const unsigned int* __restrict__ ws,
                       const float* __restrict__ x,
                       const float* __restrict__ W1, const float* __restrict__ b1,
                       const float* __restrict__ W2, const float* __restrict__ b2,
                       const float* __restrict__ W3, const float* __restrict__ b3,
                       float* __restrict__ out)
{
  __shared__ __align__(16) _Float16 hl[64];   // [0..31] real h row, [32..63] trash

  const int lane = threadIdx.x;          // 0..63 (one wave per block)
  const int half = lane >> 5;            // 0: gates i,f ; 1: gates g,o
  const int elem = blockIdx.x;

  const float A1 = half ? 2.0f : 1.0f;   // act1 = A1*rcp(1+exp2(z1)) + B1
  const float B1 = half ? -1.0f : 0.0f;  // -> sigm (lower) | tanh (upper)
  const float n2l = -2.0f * LOG2E;

  // ---- per-lane packed weights (32 dwords) + scaled consts ----
  const v4u* wp = reinterpret_cast<const v4u*>(ws + (size_t)lane * 36);
  v4u wq[8];
#pragma unroll
  for (int q = 0; q < 8; ++q) wq[q] = wp[q];
  h2 w1h[16], w2h[16];
#pragma unroll
  for (int q = 0; q < 4; ++q) {
    w1h[4*q+0] = bch2(wq[q].x);   w1h[4*q+1] = bch2(wq[q].y);
    w1h[4*q+2] = bch2(wq[q].z);   w1h[4*q+3] = bch2(wq[q].w);
    w2h[4*q+0] = bch2(wq[4+q].x); w2h[4*q+1] = bch2(wq[4+q].y);
    w2h[4*q+2] = bch2(wq[4+q].z); w2h[4*q+3] = bch2(wq[4+q].w);
  }
  const float* cf = reinterpret_cast<const float*>(ws + (size_t)lane * 36 + 32);
  const float bz1 = cf[0], bz2 = cf[1], wx1 = cf[2], wx2 = cf[3];

  float c = 0.0f;
  hl[lane] = (_Float16)0.0f;             // h0 = 0 (both rows)

  const float* xrow = x + (size_t)elem * TT;
  const v4u* hv = reinterpret_cast<const v4u*>(&hl[0]);  // 32 f16, uniform addr

#pragma unroll 1
  for (int t0 = 0; t0 < TT; t0 += 64) {
    float xc = xrow[t0 + lane];          // coalesced: 64 timesteps per load

#pragma unroll 16
    for (int s = 0; s < 64; ++s) {
      // wave-uniform x_t via v_readlane (SGPR select) — no DS op, no wait
      float xt = __builtin_bit_cast(float,
          __builtin_amdgcn_readlane(__builtin_bit_cast(unsigned, xc), s));

      float a1 = fmaf(xt, wx1, bz1);     // z seeds (bias + x-term)
      float a2 = fmaf(xt, wx2, bz2);

#pragma unroll
      for (int g = 0; g < 4; ++g) {      // h k-chunk [8g, 8g+8) as 4 half2
        v4u hq = hv[g];
        h2 p0 = bch2(hq.x), p1 = bch2(hq.y), p2 = bch2(hq.z), p3 = bch2(hq.w);
        a1 = fdot2(w1h[4*g+0], p0, a1);
        a2 = fdot2(w2h[4*g+0], p0, a2);
        a1 = fdot2(w1h[4*g+1], p1, a1);
        a2 = fdot2(w2h[4*g+1], p1, a2);
        a1 = fdot2(w1h[4*g+2], p2, a1);
        a2 = fdot2(w2h[4*g+2], p2, a2);
        a1 = fdot2(w1h[4*g+3], p3, a1);
        a2 = fdot2(w2h[4*g+3], p3, a2);
      }

      float act1 = fmaf(A1, frcp(1.0f + fexp2(a1)), B1); // sigm(i) | tanh(g)
      float act2 = frcp(1.0f + fexp2(a2));               // sigm(f) | sigm(o)

      float tg = __shfl_xor(act1, 32);   // lower <- tanh(g)   (R7-proven)
      float so = __shfl_xor(act2, 32);   // lower <- sigm(o)

      c = fmaf(act2, c, act1 * tg);      // lower: sigm(f)*c + sigm(i)*tanh(g)
      float r = frcp(1.0f + fexp2(c * n2l));  // tanh(c) = 2r - 1
      float h = fmaf(2.0f, so * r, -so); // lower: sigm(o)*tanh(c)

      hl[lane] = (_Float16)h;            // upper half -> trash slots [32..63]
    }
  }

  // ---- MLP head 32->16->8->1 on final h (LDS row 0), redundant per lane ----
  float hf[HSZ];
#pragma unroll
  for (int k = 0; k < HSZ; ++k) hf[k] = (float)hl[k];

  float a1v[16];
#pragma unroll
  for (int rr = 0; rr < 16; ++rr) {
    float acc = b1[rr];
#pragma unroll
    for (int k = 0; k < 32; ++k) acc = fmaf(W1[rr * 32 + k], hf[k], acc);
    a1v[rr] = fmaxf(acc, 0.0f);
  }
  float a2v[8];
#pragma unroll
  for (int rr = 0; rr < 8; ++rr) {
    float acc = b2[rr];
#pragma unroll
    for (int k = 0; k < 16; ++k) acc = fmaf(W2[rr * 16 + k], a1v[k], acc);
    a2v[rr] = fmaxf(acc, 0.0f);
  }
  float o = b3[0];
#pragma unroll
  for (int k = 0; k < 8; ++k) o = fmaf(W3[k], a2v[k], o);

  if (lane == 0) out[elem] = o;
}

extern "C" void kernel_launch(void* const* d_in, const int* in_sizes, int n_in,
                              void* d_out, int out_size, void* d_ws, size_t ws_size,
                              hipStream_t stream) {
  const float* x    = (const float*)d_in[0];
  const float* W_ih = (const float*)d_in[1];
  const float* W_hh = (const float*)d_in[2];
  const float* b_ih = (const float*)d_in[3];
  const float* b_hh = (const float*)d_in[4];
  const float* W1   = (const float*)d_in[5];
  const float* b1   = (const float*)d_in[6];
  const float* W2   = (const float*)d_in[7];
  const float* b2   = (const float*)d_in[8];
  const float* W3   = (const float*)d_in[9];
  const float* b3   = (const float*)d_in[10];
  float* out = (float*)d_out;
  unsigned int* ws = (unsigned int*)d_ws;    // 64*36 dwords = 9216 B

  const int B = in_sizes[0] / TT;            // 4096

  hipLaunchKernelGGL(lstm_prep_kernel, dim3(1), dim3(64), 0, stream,
                     W_ih, W_hh, b_ih, b_hh, ws);
  hipLaunchKernelGGL(lstm_fused_kernel, dim3(B), dim3(64), 0, stream,
                     ws, x, W1, b1, W2, b2, W3, b3, out);
}